// Round 6
// baseline (1291.035 us; speedup 1.0000x reference)
//
#include <hip/hip_runtime.h>
#include <cstdint>

#define TP 22528            // 256*88  (t,p) plane size
#define MROWS 90112         // 4*256*88

typedef __bf16 bf16x8 __attribute__((ext_vector_type(8)));
typedef float  f32x4  __attribute__((ext_vector_type(4)));
typedef unsigned short ushort8 __attribute__((ext_vector_type(8)));

__device__ __forceinline__ unsigned short f2bf(float x) {
    unsigned u = __builtin_bit_cast(unsigned, x);
    return (unsigned short)((u + 0x7fffu + ((u >> 16) & 1u)) >> 16);
}
__device__ __forceinline__ float bf2f(unsigned short h) {
    return __builtin_bit_cast(float, (unsigned)h << 16);
}
__device__ __forceinline__ void gl16(const void* g, void* l) {
    __builtin_amdgcn_global_load_lds(
        (const __attribute__((address_space(1))) void*)g,
        (__attribute__((address_space(3))) void*)l, 16, 0, 0);
}
__device__ __forceinline__ float rdlane(float v, int l) {
    return __builtin_bit_cast(float,
        __builtin_amdgcn_readlane(__builtin_bit_cast(int, v), l));
}

// ---------------------------------------------------------------------------
// convert all 8 weight matrices f32 -> (hi,lo) bf16, concatenated in WH/WL.
// segments: w_ih_l0(65536) w_ih_l0r(65536) w_ih_l1(32768) w_ih_l1r(32768)
//           qkv_w_t(49152) proj_w_t(16384) qkv_w_f(49152) proj_w_f(16384)
// ---------------------------------------------------------------------------
__global__ void convert_w(const float* __restrict__ s0, const float* __restrict__ s1,
                          const float* __restrict__ s2, const float* __restrict__ s3,
                          const float* __restrict__ s4, const float* __restrict__ s5,
                          const float* __restrict__ s6, const float* __restrict__ s7,
                          unsigned short* __restrict__ WH, unsigned short* __restrict__ WL)
{
    const int stride = gridDim.x * blockDim.x;
    for (int i = blockIdx.x * blockDim.x + threadIdx.x; i < 327680; i += stride) {
        const float* s; int base;
        if      (i <  65536) { s = s0; base = 0; }
        else if (i < 131072) { s = s1; base = 65536; }
        else if (i < 163840) { s = s2; base = 131072; }
        else if (i < 196608) { s = s3; base = 163840; }
        else if (i < 245760) { s = s4; base = 196608; }
        else if (i < 262144) { s = s5; base = 245760; }
        else if (i < 311296) { s = s6; base = 262144; }
        else                 { s = s7; base = 311296; }
        const float v = s[i - base];
        const unsigned short h = f2bf(v);
        WH[i] = h; WL[i] = f2bf(v - bf2f(h));
    }
}

// ---------------------------------------------------------------------------
// x (4, 256, 256, 88) f32  ->  Xhi/Xlo [m=(b,t,p)][k=256] bf16 (tiled transpose)
// ---------------------------------------------------------------------------
__launch_bounds__(256)
__global__ void transpose_x(const float* __restrict__ x,
                            unsigned short* __restrict__ Xh,
                            unsigned short* __restrict__ Xl)
{
    __shared__ float tile[64][65];
    const int tid = threadIdx.x;
    const int tp0 = blockIdx.x * 64, k0 = blockIdx.y * 64, b = blockIdx.z;
    #pragma unroll
    for (int i = 0; i < 16; ++i) {
        const int idx = i * 256 + tid;
        const int kl = idx >> 6, tpl = idx & 63;
        tile[kl][tpl] = x[(size_t)(b * 256 + k0 + kl) * TP + tp0 + tpl];
    }
    __syncthreads();
    #pragma unroll
    for (int i = 0; i < 2; ++i) {
        const int u = i * 2048 + tid * 8;
        const int ml = u >> 6, kl0 = u & 63;
        ushort8 hi, lo;
        #pragma unroll
        for (int j = 0; j < 8; ++j) {
            const float v = tile[kl0 + j][ml];
            const unsigned short h = f2bf(v);
            hi[j] = h; lo[j] = f2bf(v - bf2f(h));
        }
        const size_t row = (size_t)b * TP + tp0 + ml;
        *(ushort8*)&Xh[row * 256 + k0 + kl0] = hi;
        *(ushort8*)&Xl[row * 256 + k0 + kl0] = lo;
    }
}

// ---------------------------------------------------------------------------
// MFMA split-bf16 GEMM, pre-converted operands.
// C[m, n0+n] = bias[n] + sum_k A[m,k]*W[n,k],  A=(Ahi+Alo), W=(Whi+Wlo),
// products: hh + hl + lh (3 mfma). Tile 128x128, BK=32, 4 waves 2x2 (64x64
// each). Double-buffered 64 KB LDS staged via global_load_lds (16B), counted
// vmcnt(8), raw s_barrier. Read-side XOR swizzle slot^=(row&3) paired with
// inverse-swizzled global source (both-sides involution).
// Blocks with n0>=splitN use W1 set. NB = N/128; grid = 704*NB (div by 8).
// ---------------------------------------------------------------------------
template<int OUTBF>
__launch_bounds__(256, 2)
__global__ void gemm_bf16(const unsigned short* __restrict__ Ahi,
                          const unsigned short* __restrict__ Alo,
                          const unsigned short* __restrict__ Whi0,
                          const unsigned short* __restrict__ Wlo0,
                          const unsigned short* __restrict__ Whi1,
                          const unsigned short* __restrict__ Wlo1,
                          const float* __restrict__ b0a, const float* __restrict__ b0b,
                          const float* __restrict__ b1a, const float* __restrict__ b1b,
                          float* __restrict__ C,
                          unsigned short* __restrict__ Chi, unsigned short* __restrict__ Clo,
                          int ldc, int K, int splitN, int NB)
{
    __shared__ unsigned short lds[32768];   // 2 bufs x (AH|AL|BH|BL) x 8KB
    const int tid  = threadIdx.x;
    const int bid  = blockIdx.x;
    const int q8   = (int)gridDim.x >> 3;
    const int wq   = (bid & 7) * q8 + (bid >> 3);   // bijective XCD swizzle
    const int nb   = wq % NB;
    const int mb   = wq / NB;
    const int n0   = nb * 128;
    const int m0   = mb * 128;
    const unsigned short* Wh; const unsigned short* Wl;
    const float* ba; const float* bb; int nr0;
    if (n0 < splitN) { Wh = Whi0; Wl = Wlo0; ba = b0a; bb = b0b; nr0 = n0; }
    else             { Wh = Whi1; Wl = Wlo1; ba = b1a; bb = b1b; nr0 = n0 - splitN; }
    const int lane = tid & 63;
    const int wv   = tid >> 6;
    const int wm   = wv >> 1, wn = wv & 1;
    const int lr   = lane & 15, lg = lane >> 4;
    // staging: lane covers row (l>>2) of its 16-row chunk, slot (l&3);
    // source slot pre-swizzled by row&3 (inverse of the read-side XOR).
    const int voff = (lane >> 2) * K + (((lane & 3) ^ ((lane >> 2) & 3)) * 8);
    const int wb   = wv * 1024;                      // wave's LDS row area

    const unsigned short* gAh = Ahi + (size_t)(m0 + wv * 32) * K + voff;
    const unsigned short* gAl = Alo + (size_t)(m0 + wv * 32) * K + voff;
    const unsigned short* gBh = Wh + (size_t)(nr0 + wv * 32) * K + voff;
    const unsigned short* gBl = Wl + (size_t)(nr0 + wv * 32) * K + voff;

    const int NT = K >> 5;
    f32x4 acc[4][4] = {};

    auto stage = [&](int bufi, int ks) {
        unsigned short* base = lds + bufi * 16384;
        gl16(gAh + ks,          base +         wb);
        gl16(gAh + ks + 16 * K, base +         wb + 512);
        gl16(gAl + ks,          base + 4096  + wb);
        gl16(gAl + ks + 16 * K, base + 4096  + wb + 512);
        gl16(gBh + ks,          base + 8192  + wb);
        gl16(gBh + ks + 16 * K, base + 8192  + wb + 512);
        gl16(gBl + ks,          base + 12288 + wb);
        gl16(gBl + ks + 16 * K, base + 12288 + wb + 512);
    };

    stage(0, 0);
    for (int t = 0; t < NT; ++t) {
        const int cur = (t & 1) * 16384;
        if (t + 1 < NT) {
            stage((t & 1) ^ 1, (t + 1) * 32);
            asm volatile("s_waitcnt vmcnt(8)" ::: "memory");
        } else {
            asm volatile("s_waitcnt vmcnt(0)" ::: "memory");
        }
        __builtin_amdgcn_s_barrier();
        __builtin_amdgcn_sched_barrier(0);
        bf16x8 ah[4], al[4], bh[4], bl[4];
        #pragma unroll
        for (int mf = 0; mf < 4; ++mf) {
            const int r = wm * 64 + mf * 16 + lr;
            const int o = r * 32 + ((lg ^ (r & 3)) * 8);
            ah[mf] = *(const bf16x8*)&lds[cur + o];
            al[mf] = *(const bf16x8*)&lds[cur + 4096 + o];
        }
        #pragma unroll
        for (int nf = 0; nf < 4; ++nf) {
            const int r = wn * 64 + nf * 16 + lr;
            const int o = r * 32 + ((lg ^ (r & 3)) * 8);
            bh[nf] = *(const bf16x8*)&lds[cur + 8192 + o];
            bl[nf] = *(const bf16x8*)&lds[cur + 12288 + o];
        }
        #pragma unroll
        for (int mf = 0; mf < 4; ++mf)
            #pragma unroll
            for (int nf = 0; nf < 4; ++nf) {
                acc[mf][nf] = __builtin_amdgcn_mfma_f32_16x16x32_bf16(ah[mf], bh[nf], acc[mf][nf], 0, 0, 0);
                acc[mf][nf] = __builtin_amdgcn_mfma_f32_16x16x32_bf16(ah[mf], bl[nf], acc[mf][nf], 0, 0, 0);
                acc[mf][nf] = __builtin_amdgcn_mfma_f32_16x16x32_bf16(al[mf], bh[nf], acc[mf][nf], 0, 0, 0);
            }
        __builtin_amdgcn_s_barrier();
        __builtin_amdgcn_sched_barrier(0);
    }
    // epilogue: D frag col=lane&15, row=(lane>>4)*4+reg  [m89]
    #pragma unroll
    for (int nf = 0; nf < 4; ++nf) {
        const int ncol = wn * 64 + nf * 16 + lr;
        const float bias = ba[nr0 + ncol] + (bb ? bb[nr0 + ncol] : 0.0f);
        #pragma unroll
        for (int mf = 0; mf < 4; ++mf) {
            const int row = m0 + wm * 64 + mf * 16 + lg * 4;
            #pragma unroll
            for (int i = 0; i < 4; ++i) {
                const float v = acc[mf][nf][i] + bias;
                if (OUTBF) {
                    const size_t o = (size_t)(row + i) * ldc + n0 + ncol;
                    const unsigned short h = f2bf(v);
                    Chi[o] = h; Clo[o] = f2bf(v - bf2f(h));
                } else {
                    C[(size_t)(row + i) * ldc + n0 + ncol] = v;
                }
            }
        }
    }
}

// ---------------------------------------------------------------------------
// LSTM recurrence. One block per (sequence row n, direction).
// XI: [MROWS][512] f32 precomputed x@W_ih^T + b_ih + b_hh. H out: hi/lo bf16
// planes [MROWS][128] (fwd cols 0..63, bwd 64..127). Gate order i|f|g|o.
// Thread j owns gate j; h broadcast via ONE ds_read_b128 per wave + in-reg
// v_readlane (compile-time lanes) -> removes the per-step 16x uniform-LDS-read
// bottleneck (LDS pipe is per-CU and was the 2112 cy/step limiter).
// ---------------------------------------------------------------------------
__launch_bounds__(256)
__global__ void lstm_kernel(const float* __restrict__ XI,
                            const float* __restrict__ whh_f,
                            const float* __restrict__ whh_b,
                            unsigned short* __restrict__ Hh,
                            unsigned short* __restrict__ Hl)
{
    const int bid = blockIdx.x;      // 0..703
    const int dir = bid & 1;
    const int n   = bid >> 1;        // 0..351
    const int b   = n / 88, p = n - 88 * (n / 88);
    const int j   = threadIdx.x;
    const int lane = j & 63;
    const float* whh = dir ? whh_b : whh_f;
    const int j0 = dir ? 256 : 0;
    const int ho = dir ? 64 : 0;
    float w[64];
    #pragma unroll
    for (int k = 0; k < 64; k += 4) {
        const float4 wv = *(const float4*)(whh + (size_t)j * 64 + k);
        w[k] = wv.x; w[k+1] = wv.y; w[k+2] = wv.z; w[k+3] = wv.w;
    }
    __shared__ float h_sh[64];
    __shared__ float acts[256];
    if (j < 64) h_sh[j] = 0.0f;
    float c = 0.0f;
    __syncthreads();
    const size_t rowbase = (size_t)(b * 256) * 88 + p;
    float pref = XI[(rowbase + (size_t)(dir ? 255 : 0) * 88) * 512 + j0 + j];
    for (int step = 0; step < 256; ++step) {
        const int t = dir ? (255 - step) : step;
        const size_t r = rowbase + (size_t)t * 88;
        // one ds_read_b128 per wave: lane l&15 holds h[(l&15)*4 .. +3]
        const float4 hc = *(const float4*)&h_sh[(lane & 15) * 4];
        float gs0 = pref, gs1 = 0.0f, gs2 = 0.0f, gs3 = 0.0f;
        if (step + 1 < 256) {   // prefetch next step's xi (hides HBM latency)
            const int tn = dir ? (254 - step) : (step + 1);
            pref = XI[(rowbase + (size_t)tn * 88) * 512 + j0 + j];
        }
        // h[k] lives in lane k>>2, elem k&3 -> v_readlane broadcast (no LDS)
        #pragma unroll
        for (int kq = 0; kq < 16; ++kq) {
            gs0 += rdlane(hc.x, kq) * w[kq * 4 + 0];
            gs1 += rdlane(hc.y, kq) * w[kq * 4 + 1];
            gs2 += rdlane(hc.z, kq) * w[kq * 4 + 2];
            gs3 += rdlane(hc.w, kq) * w[kq * 4 + 3];
        }
        const float g = (gs0 + gs1) + (gs2 + gs3);
        float a;
        if (j >= 128 && j < 192) {            // g-gate: tanh (wave-uniform)
            const float e = __expf(2.0f * g);
            a = 1.0f - 2.0f / (e + 1.0f);
        } else {                              // i,f,o: sigmoid
            a = 1.0f / (1.0f + __expf(-g));
        }
        if (j >= 64) acts[j] = a;             // wave 0 keeps i-gate local
        __syncthreads();
        if (j < 64) {
            const float ai = a, af = acts[64 + j], ag = acts[128 + j], ao = acts[192 + j];
            c = af * c + ai * ag;
            const float e = __expf(2.0f * c);
            const float th = 1.0f - 2.0f / (e + 1.0f);
            const float h = ao * th;
            h_sh[j] = h;
            const size_t o = r * 128 + ho + j;
            const unsigned short hh = f2bf(h);
            Hh[o] = hh; Hl[o] = f2bf(h - bf2f(hh));
        }
        __syncthreads();
    }
}

// ---------------------------------------------------------------------------
// NA1D over t, kernel=7, heads=1. One wave per query row.
// QKV: [MROWS][384] f32 (q|k|v). OUT: hi/lo bf16 [MROWS][128].
// ---------------------------------------------------------------------------
__launch_bounds__(256)
__global__ void na_t_kernel(const float* __restrict__ QKV,
                            const float* __restrict__ rpb,
                            unsigned short* __restrict__ OUTh,
                            unsigned short* __restrict__ OUTl)
{
    const int wave = threadIdx.x >> 6;
    const int lane = threadIdx.x & 63;
    const int q = blockIdx.x * 4 + wave;          // row r = (b*256+i)*88+p
    const int b = q / TP; int rem = q - b * TP;
    const int i = rem / 88; const int p = rem - 88 * (rem / 88);
    int start = i - 3; if (start < 0) start = 0; if (start > 249) start = 249;
    const float scale = 0.08838834764831845f;     // 128^-0.5
    const float* qrow = QKV + (size_t)q * 384;
    const float q0 = qrow[lane] * scale;
    const float q1 = qrow[lane + 64] * scale;
    const size_t rbase = (size_t)(b * 256) * 88 + p;
    float s[7];
    #pragma unroll
    for (int jj = 0; jj < 7; ++jj) {
        const int t = start + jj;
        const float* krow = QKV + (rbase + (size_t)t * 88) * 384 + 128;
        float part = q0 * krow[lane] + q1 * krow[lane + 64];
        part += __shfl_xor(part, 1);
        part += __shfl_xor(part, 2);
        part += __shfl_xor(part, 4);
        part += __shfl_xor(part, 8);
        part += __shfl_xor(part, 16);
        part += __shfl_xor(part, 32);
        int rel = t - i + 6; if (rel < 0) rel = 0; if (rel > 12) rel = 12;
        s[jj] = part + rpb[rel];
    }
    float m = s[0];
    #pragma unroll
    for (int jj = 1; jj < 7; ++jj) m = fmaxf(m, s[jj]);
    float sum = 0.0f;
    #pragma unroll
    for (int jj = 0; jj < 7; ++jj) { s[jj] = __expf(s[jj] - m); sum += s[jj]; }
    const float inv = 1.0f / sum;
    float o0 = 0.0f, o1 = 0.0f;
    #pragma unroll
    for (int jj = 0; jj < 7; ++jj) {
        const float* vrow = QKV + (rbase + (size_t)(start + jj) * 88) * 384 + 256;
        const float pj = s[jj] * inv;
        o0 += pj * vrow[lane];
        o1 += pj * vrow[lane + 64];
    }
    const size_t oi = (size_t)q * 128 + lane;
    const unsigned short h0 = f2bf(o0);
    OUTh[oi] = h0; OUTl[oi] = f2bf(o0 - bf2f(h0));
    const unsigned short h1 = f2bf(o1);
    OUTh[oi + 64] = h1; OUTl[oi + 64] = f2bf(o1 - bf2f(h1));
}

// ---------------------------------------------------------------------------
// NA1D over p, kernel=87, L=88, heads=1. One block per (b,t).
// Excluded key: j=87 when i<=43, j=0 when i>=44. OUT: hi/lo bf16.
// ---------------------------------------------------------------------------
#define LPAD 133
#define SPAD 89
__launch_bounds__(256)
__global__ void na_f_kernel(const float* __restrict__ QKV,
                            const float* __restrict__ rpb,
                            unsigned short* __restrict__ OUTh,
                            unsigned short* __restrict__ OUTl)
{
    __shared__ float Qs[96][LPAD];
    __shared__ float Ks[96][LPAD];   // reused for V in PV phase
    __shared__ float Ss[96][SPAD];
    const int blk = blockIdx.x;                      // b*256 + t
    const int tid = threadIdx.x;
    const size_t base = (size_t)blk * 88 * 384;
    const float scale = 0.08838834764831845f;
    for (int f = tid; f < 2816; f += 256) {
        const int row = f >> 5, c4 = (f & 31) * 4;
        const float4 qv = *(const float4*)(QKV + base + (size_t)row * 384 + c4);
        Qs[row][c4+0] = qv.x * scale; Qs[row][c4+1] = qv.y * scale;
        Qs[row][c4+2] = qv.z * scale; Qs[row][c4+3] = qv.w * scale;
        const float4 kv = *(const float4*)(QKV + base + (size_t)row * 384 + 128 + c4);
        Ks[row][c4+0] = kv.x; Ks[row][c4+1] = kv.y;
        Ks[row][c4+2] = kv.z; Ks[row][c4+3] = kv.w;
    }
    __syncthreads();
    const int tx = tid & 15, ty = tid >> 4;
    { // S = Q K^T
        float acc[6][6] = {};
        for (int kk = 0; kk < 128; ++kk) {
            float a[6], bb[6];
            #pragma unroll
            for (int i = 0; i < 6; ++i) a[i] = Qs[ty*6 + i][kk];
            #pragma unroll
            for (int j = 0; j < 6; ++j) bb[j] = Ks[tx*6 + j][kk];
            #pragma unroll
            for (int i = 0; i < 6; ++i)
                #pragma unroll
                for (int j = 0; j < 6; ++j)
                    acc[i][j] += a[i] * bb[j];
        }
        #pragma unroll
        for (int i = 0; i < 6; ++i) {
            const int qq = ty*6 + i;
            if (qq < 88) {
                #pragma unroll
                for (int j = 0; j < 6; ++j) {
                    const int k = tx*6 + j;
                    if (k < 88) Ss[qq][k] = acc[i][j];
                }
            }
        }
    }
    __syncthreads();
    // stage V into Ks region (K no longer needed)
    for (int f = tid; f < 2816; f += 256) {
        const int row = f >> 5, c4 = (f & 31) * 4;
        const float4 vv = *(const float4*)(QKV + base + (size_t)row * 384 + 256 + c4);
        Ks[row][c4+0] = vv.x; Ks[row][c4+1] = vv.y;
        Ks[row][c4+2] = vv.z; Ks[row][c4+3] = vv.w;
    }
    if (tid < 88) {
        const int i = tid;
        const int jex = (i <= 43) ? 87 : 0;
        float m = -1e30f;
        for (int k = 0; k < 88; ++k) {
            if (k == jex) continue;
            int rel = k - i + 86; if (rel < 0) rel = 0; if (rel > 172) rel = 172;
            const float v = Ss[i][k] + rpb[rel];
            Ss[i][k] = v;
            m = fmaxf(m, v);
        }
        float sum = 0.0f;
        for (int k = 0; k < 88; ++k) {
            if (k == jex) continue;
            const float e = __expf(Ss[i][k] - m);
            Ss[i][k] = e;
            sum += e;
        }
        const float inv = 1.0f / sum;
        for (int k = 0; k < 88; ++k) Ss[i][k] = (k == jex) ? 0.0f : Ss[i][k] * inv;
    }
    __syncthreads();
    { // O = P V
        float o[6][8] = {};
        for (int k = 0; k < 88; ++k) {
            float pv[6], vv[8];
            #pragma unroll
            for (int i = 0; i < 6; ++i) pv[i] = Ss[ty*6 + i][k];
            #pragma unroll
            for (int j = 0; j < 8; ++j) vv[j] = Ks[k][tx + 16*j];
            #pragma unroll
            for (int i = 0; i < 6; ++i)
                #pragma unroll
                for (int j = 0; j < 8; ++j)
                    o[i][j] += pv[i] * vv[j];
        }
        #pragma unroll
        for (int i = 0; i < 6; ++i) {
            const int qq = ty*6 + i;
            if (qq < 88) {
                const size_t ro = ((size_t)blk * 88 + qq) * 128;
                #pragma unroll
                for (int j = 0; j < 8; ++j) {
                    const float v = o[i][j];
                    const unsigned short hh = f2bf(v);
                    OUTh[ro + tx + 16*j] = hh;
                    OUTl[ro + tx + 16*j] = f2bf(v - bf2f(hh));
                }
            }
        }
    }
}

// ---------------------------------------------------------------------------
extern "C" void kernel_launch(void* const* d_in, const int* in_sizes, int n_in,
                              void* d_out, int out_size, void* d_ws, size_t ws_size,
                              hipStream_t stream)
{
    const float* x         = (const float*)d_in[0];
    const float* w_ih_l0   = (const float*)d_in[1];
    const float* w_hh_l0   = (const float*)d_in[2];
    const float* b_ih_l0   = (const float*)d_in[3];
    const float* b_hh_l0   = (const float*)d_in[4];
    const float* w_ih_l0r  = (const float*)d_in[5];
    const float* w_hh_l0r  = (const float*)d_in[6];
    const float* b_ih_l0r  = (const float*)d_in[7];
    const float* b_hh_l0r  = (const float*)d_in[8];
    const float* w_ih_l1   = (const float*)d_in[9];
    const float* w_hh_l1   = (const float*)d_in[10];
    const float* b_ih_l1   = (const float*)d_in[11];
    const float* b_hh_l1   = (const float*)d_in[12];
    const float* w_ih_l1r  = (const float*)d_in[13];
    const float* w_hh_l1r  = (const float*)d_in[14];
    const float* b_ih_l1r  = (const float*)d_in[15];
    const float* b_hh_l1r  = (const float*)d_in[16];
    const float* qkv_w_t   = (const float*)d_in[17];
    const float* qkv_b_t   = (const float*)d_in[18];
    const float* rpb_t     = (const float*)d_in[19];
    const float* proj_w_t  = (const float*)d_in[20];
    const float* proj_b_t  = (const float*)d_in[21];
    const float* qkv_w_f   = (const float*)d_in[22];
    const float* qkv_b_f   = (const float*)d_in[23];
    const float* rpb_f     = (const float*)d_in[24];
    const float* proj_w_f  = (const float*)d_in[25];
    const float* proj_b_f  = (const float*)d_in[26];

    // Workspace (floats from base), ~278 MB:
    //  [0 .. 46,137,344)           XI f32 [MROWS][512]; later QKV f32
    //                              [MROWS][384] at base + ATT hi/lo pair in
    //                              the tail (exactly fits).
    //  [46,137,344 .. 57,671,680)  H hi/lo pair   (overlaid by Xhi initially)
    //  [57,671,680 .. 69,206,016)  G hi/lo pair   (overlaid by Xlo initially)
    //  [69,206,016 .. 69,533,696)  WH | WL weight bf16 pairs
    float* ws = (float*)d_ws;
    float*          XI   = ws;
    float*          QKV  = ws;
    unsigned short* ATTh = (unsigned short*)(ws + (size_t)MROWS * 384);
    unsigned short* ATTl = ATTh + (size_t)MROWS * 128;
    unsigned short* Hh   = (unsigned short*)(ws + 46137344);
    unsigned short* Hl   = Hh + (size_t)MROWS * 128;
    unsigned short* Gh   = (unsigned short*)(ws + 57671680);
    unsigned short* Gl   = Gh + (size_t)MROWS * 128;
    unsigned short* Xh   = (unsigned short*)(ws + 46137344);  // overlay H+G
    unsigned short* Xl   = Xh + (size_t)MROWS * 256;
    unsigned short* WH   = (unsigned short*)(ws + 69206016);
    unsigned short* WL   = WH + 327680;

    const int BIG = 1 << 30;
    const dim3 blk(256);

    convert_w<<<dim3(320), blk, 0, stream>>>(w_ih_l0, w_ih_l0r, w_ih_l1, w_ih_l1r,
        qkv_w_t, proj_w_t, qkv_w_f, proj_w_f, WH, WL);
    transpose_x<<<dim3(352, 4, 4), blk, 0, stream>>>(x, Xh, Xl);
    // 1) layer-0 input projection
    gemm_bf16<0><<<dim3(2816), blk, 0, stream>>>(Xh, Xl,
        WH, WL, WH + 65536, WL + 65536,
        b_ih_l0, b_hh_l0, b_ih_l0r, b_hh_l0r,
        XI, nullptr, nullptr, 512, 256, 256, 4);
    // 2) layer-0 recurrence
    lstm_kernel<<<dim3(704), blk, 0, stream>>>(XI, w_hh_l0, w_hh_l0r, Hh, Hl);
    // 3) layer-1 input projection
    gemm_bf16<0><<<dim3(2816), blk, 0, stream>>>(Hh, Hl,
        WH + 131072, WL + 131072, WH + 163840, WL + 163840,
        b_ih_l1, b_hh_l1, b_ih_l1r, b_hh_l1r,
        XI, nullptr, nullptr, 512, 128, 256, 4);
    // 4) layer-1 recurrence
    lstm_kernel<<<dim3(704), blk, 0, stream>>>(XI, w_hh_l1, w_hh_l1r, Hh, Hl);
    // 5) QKV for NA over t
    gemm_bf16<0><<<dim3(2112), blk, 0, stream>>>(Hh, Hl,
        WH + 196608, WL + 196608, WH + 196608, WL + 196608,
        qkv_b_t, nullptr, qkv_b_t, nullptr,
        QKV, nullptr, nullptr, 384, 128, BIG, 3);
    // 6) NA over t (kernel=7)
    na_t_kernel<<<dim3(22528), blk, 0, stream>>>(QKV, rpb_t, ATTh, ATTl);
    // 7) proj_t -> G (bf16 pair out)
    gemm_bf16<1><<<dim3(704), blk, 0, stream>>>(ATTh, ATTl,
        WH + 245760, WL + 245760, WH + 245760, WL + 245760,
        proj_b_t, nullptr, proj_b_t, nullptr,
        nullptr, Gh, Gl, 128, 128, BIG, 1);
    // 8) QKV for NA over p
    gemm_bf16<0><<<dim3(2112), blk, 0, stream>>>(Gh, Gl,
        WH + 262144, WL + 262144, WH + 262144, WL + 262144,
        qkv_b_f, nullptr, qkv_b_f, nullptr,
        QKV, nullptr, nullptr, 384, 128, BIG, 3);
    // 9) NA over p (kernel=87)
    na_f_kernel<<<dim3(1024), blk, 0, stream>>>(QKV, rpb_f, ATTh, ATTl);
    // 10) proj_f -> final output
    gemm_bf16<0><<<dim3(704), blk, 0, stream>>>(ATTh, ATTl,
        WH + 311296, WL + 311296, WH + 311296, WL + 311296,
        proj_b_f, nullptr, proj_b_f, nullptr,
        (float*)d_out, nullptr, nullptr, 128, 128, BIG, 1);
}

// Round 7
// 1171.594 us; speedup vs baseline: 1.1019x; 1.1019x over previous
//
#include <hip/hip_runtime.h>
#include <cstdint>

#define TP 22528            // 256*88  (t,p) plane size
#define MROWS 90112         // 4*256*88

typedef __bf16 bf16x8 __attribute__((ext_vector_type(8)));
typedef float  f32x4  __attribute__((ext_vector_type(4)));
typedef unsigned short ushort8 __attribute__((ext_vector_type(8)));

__device__ __forceinline__ unsigned short f2bf(float x) {
    unsigned u = __builtin_bit_cast(unsigned, x);
    return (unsigned short)((u + 0x7fffu + ((u >> 16) & 1u)) >> 16);
}
__device__ __forceinline__ float bf2f(unsigned short h) {
    return __builtin_bit_cast(float, (unsigned)h << 16);
}
__device__ __forceinline__ void gl16(const void* g, void* l) {
    __builtin_amdgcn_global_load_lds(
        (const __attribute__((address_space(1))) void*)g,
        (__attribute__((address_space(3))) void*)l, 16, 0, 0);
}

// ---------------------------------------------------------------------------
// convert all 8 weight matrices f32 -> (hi,lo) bf16, concatenated in WH/WL.
// segments: w_ih_l0(65536) w_ih_l0r(65536) w_ih_l1(32768) w_ih_l1r(32768)
//           qkv_w_t(49152) proj_w_t(16384) qkv_w_f(49152) proj_w_f(16384)
// ---------------------------------------------------------------------------
__global__ void convert_w(const float* __restrict__ s0, const float* __restrict__ s1,
                          const float* __restrict__ s2, const float* __restrict__ s3,
                          const float* __restrict__ s4, const float* __restrict__ s5,
                          const float* __restrict__ s6, const float* __restrict__ s7,
                          unsigned short* __restrict__ WH, unsigned short* __restrict__ WL)
{
    const int stride = gridDim.x * blockDim.x;
    for (int i = blockIdx.x * blockDim.x + threadIdx.x; i < 327680; i += stride) {
        const float* s; int base;
        if      (i <  65536) { s = s0; base = 0; }
        else if (i < 131072) { s = s1; base = 65536; }
        else if (i < 163840) { s = s2; base = 131072; }
        else if (i < 196608) { s = s3; base = 163840; }
        else if (i < 245760) { s = s4; base = 196608; }
        else if (i < 262144) { s = s5; base = 245760; }
        else if (i < 311296) { s = s6; base = 262144; }
        else                 { s = s7; base = 311296; }
        const float v = s[i - base];
        const unsigned short h = f2bf(v);
        WH[i] = h; WL[i] = f2bf(v - bf2f(h));
    }
}

// ---------------------------------------------------------------------------
// x (4, 256, 256, 88) f32  ->  Xhi/Xlo [m=(b,t,p)][k=256] bf16 (tiled transpose)
// ---------------------------------------------------------------------------
__launch_bounds__(256)
__global__ void transpose_x(const float* __restrict__ x,
                            unsigned short* __restrict__ Xh,
                            unsigned short* __restrict__ Xl)
{
    __shared__ float tile[64][65];
    const int tid = threadIdx.x;
    const int tp0 = blockIdx.x * 64, k0 = blockIdx.y * 64, b = blockIdx.z;
    #pragma unroll
    for (int i = 0; i < 16; ++i) {
        const int idx = i * 256 + tid;
        const int kl = idx >> 6, tpl = idx & 63;
        tile[kl][tpl] = x[(size_t)(b * 256 + k0 + kl) * TP + tp0 + tpl];
    }
    __syncthreads();
    #pragma unroll
    for (int i = 0; i < 2; ++i) {
        const int u = i * 2048 + tid * 8;
        const int ml = u >> 6, kl0 = u & 63;
        ushort8 hi, lo;
        #pragma unroll
        for (int j = 0; j < 8; ++j) {
            const float v = tile[kl0 + j][ml];
            const unsigned short h = f2bf(v);
            hi[j] = h; lo[j] = f2bf(v - bf2f(h));
        }
        const size_t row = (size_t)b * TP + tp0 + ml;
        *(ushort8*)&Xh[row * 256 + k0 + kl0] = hi;
        *(ushort8*)&Xl[row * 256 + k0 + kl0] = lo;
    }
}

// ---------------------------------------------------------------------------
// MFMA split-bf16 GEMM, pre-converted operands.
// C[m, n0+n] = bias[n] + sum_k A[m,k]*W[n,k],  A=(Ahi+Alo), W=(Whi+Wlo),
// products: hh + hl + lh (3 mfma). Tile 128x128, BK=32, 4 waves 2x2 (64x64
// each). Double-buffered 64 KB LDS staged via global_load_lds (16B), counted
// vmcnt(8), raw s_barrier. Read-side XOR swizzle slot^=(row&3) paired with
// inverse-swizzled global source (both-sides involution).
// Blocks with n0>=splitN use W1 set. NB = N/128; grid = 704*NB (div by 8).
// ---------------------------------------------------------------------------
template<int OUTBF>
__launch_bounds__(256, 2)
__global__ void gemm_bf16(const unsigned short* __restrict__ Ahi,
                          const unsigned short* __restrict__ Alo,
                          const unsigned short* __restrict__ Whi0,
                          const unsigned short* __restrict__ Wlo0,
                          const unsigned short* __restrict__ Whi1,
                          const unsigned short* __restrict__ Wlo1,
                          const float* __restrict__ b0a, const float* __restrict__ b0b,
                          const float* __restrict__ b1a, const float* __restrict__ b1b,
                          float* __restrict__ C,
                          unsigned short* __restrict__ Chi, unsigned short* __restrict__ Clo,
                          int ldc, int K, int splitN, int NB)
{
    __shared__ unsigned short lds[32768];   // 2 bufs x (AH|AL|BH|BL) x 8KB
    const int tid  = threadIdx.x;
    const int bid  = blockIdx.x;
    const int q8   = (int)gridDim.x >> 3;
    const int wq   = (bid & 7) * q8 + (bid >> 3);   // bijective XCD swizzle
    const int nb   = wq % NB;
    const int mb   = wq / NB;
    const int n0   = nb * 128;
    const int m0   = mb * 128;
    const unsigned short* Wh; const unsigned short* Wl;
    const float* ba; const float* bb; int nr0;
    if (n0 < splitN) { Wh = Whi0; Wl = Wlo0; ba = b0a; bb = b0b; nr0 = n0; }
    else             { Wh = Whi1; Wl = Wlo1; ba = b1a; bb = b1b; nr0 = n0 - splitN; }
    const int lane = tid & 63;
    const int wv   = tid >> 6;
    const int wm   = wv >> 1, wn = wv & 1;
    const int lr   = lane & 15, lg = lane >> 4;
    // staging: lane covers row (l>>2) of its 16-row chunk, slot (l&3);
    // source slot pre-swizzled by row&3 (inverse of the read-side XOR).
    const int voff = (lane >> 2) * K + (((lane & 3) ^ ((lane >> 2) & 3)) * 8);
    const int wb   = wv * 1024;                      // wave's LDS row area

    const unsigned short* gAh = Ahi + (size_t)(m0 + wv * 32) * K + voff;
    const unsigned short* gAl = Alo + (size_t)(m0 + wv * 32) * K + voff;
    const unsigned short* gBh = Wh + (size_t)(nr0 + wv * 32) * K + voff;
    const unsigned short* gBl = Wl + (size_t)(nr0 + wv * 32) * K + voff;

    const int NT = K >> 5;
    f32x4 acc[4][4] = {};

    auto stage = [&](int bufi, int ks) {
        unsigned short* base = lds + bufi * 16384;
        gl16(gAh + ks,          base +         wb);
        gl16(gAh + ks + 16 * K, base +         wb + 512);
        gl16(gAl + ks,          base + 4096  + wb);
        gl16(gAl + ks + 16 * K, base + 4096  + wb + 512);
        gl16(gBh + ks,          base + 8192  + wb);
        gl16(gBh + ks + 16 * K, base + 8192  + wb + 512);
        gl16(gBl + ks,          base + 12288 + wb);
        gl16(gBl + ks + 16 * K, base + 12288 + wb + 512);
    };

    stage(0, 0);
    for (int t = 0; t < NT; ++t) {
        const int cur = (t & 1) * 16384;
        if (t + 1 < NT) {
            stage((t & 1) ^ 1, (t + 1) * 32);
            asm volatile("s_waitcnt vmcnt(8)" ::: "memory");
        } else {
            asm volatile("s_waitcnt vmcnt(0)" ::: "memory");
        }
        __builtin_amdgcn_s_barrier();
        __builtin_amdgcn_sched_barrier(0);
        bf16x8 ah[4], al[4], bh[4], bl[4];
        #pragma unroll
        for (int mf = 0; mf < 4; ++mf) {
            const int r = wm * 64 + mf * 16 + lr;
            const int o = r * 32 + ((lg ^ (r & 3)) * 8);
            ah[mf] = *(const bf16x8*)&lds[cur + o];
            al[mf] = *(const bf16x8*)&lds[cur + 4096 + o];
        }
        #pragma unroll
        for (int nf = 0; nf < 4; ++nf) {
            const int r = wn * 64 + nf * 16 + lr;
            const int o = r * 32 + ((lg ^ (r & 3)) * 8);
            bh[nf] = *(const bf16x8*)&lds[cur + 8192 + o];
            bl[nf] = *(const bf16x8*)&lds[cur + 12288 + o];
        }
        #pragma unroll
        for (int mf = 0; mf < 4; ++mf)
            #pragma unroll
            for (int nf = 0; nf < 4; ++nf) {
                acc[mf][nf] = __builtin_amdgcn_mfma_f32_16x16x32_bf16(ah[mf], bh[nf], acc[mf][nf], 0, 0, 0);
                acc[mf][nf] = __builtin_amdgcn_mfma_f32_16x16x32_bf16(ah[mf], bl[nf], acc[mf][nf], 0, 0, 0);
                acc[mf][nf] = __builtin_amdgcn_mfma_f32_16x16x32_bf16(al[mf], bh[nf], acc[mf][nf], 0, 0, 0);
            }
        __builtin_amdgcn_s_barrier();
        __builtin_amdgcn_sched_barrier(0);
    }
    // epilogue: D frag col=lane&15, row=(lane>>4)*4+reg  [m89]
    #pragma unroll
    for (int nf = 0; nf < 4; ++nf) {
        const int ncol = wn * 64 + nf * 16 + lr;
        const float bias = ba[nr0 + ncol] + (bb ? bb[nr0 + ncol] : 0.0f);
        #pragma unroll
        for (int mf = 0; mf < 4; ++mf) {
            const int row = m0 + wm * 64 + mf * 16 + lg * 4;
            #pragma unroll
            for (int i = 0; i < 4; ++i) {
                const float v = acc[mf][nf][i] + bias;
                if (OUTBF) {
                    const size_t o = (size_t)(row + i) * ldc + n0 + ncol;
                    const unsigned short h = f2bf(v);
                    Chi[o] = h; Clo[o] = f2bf(v - bf2f(h));
                } else {
                    C[(size_t)(row + i) * ldc + n0 + ncol] = v;
                }
            }
        }
    }
}

// ---------------------------------------------------------------------------
// LSTM recurrence, 2 gates per thread. One 128-thread block per (row, dir).
// wave0 lane u: gates i_u (row u) and g_u (row 128+u); computes ig = i*g.
// wave1 lane u: gates f_u (row 64+u) and o_u (row 192+u); owns c_u, h_u.
// Rationale: the h-broadcast (16 uniform ds_read_b128 per thread per step)
// is the per-CU LDS-pipe bottleneck; its cost = waves/CU x issues/wave.
// 2 gates/thread halves waves/CU (5.5 vs 11) at same issues/wave ->
// ~1120 cy/step vs measured 2112 (r4) / 3060 (r6 readlane). VALU stays
// non-binding (1.375 waves/SIMD x ~260 cy). Math identical f32.
// ---------------------------------------------------------------------------
__launch_bounds__(128)
__global__ void lstm_kernel(const float* __restrict__ XI,
                            const float* __restrict__ whh_f,
                            const float* __restrict__ whh_b,
                            unsigned short* __restrict__ Hh,
                            unsigned short* __restrict__ Hl)
{
    const int bid = blockIdx.x;      // 0..703
    const int dir = bid & 1;
    const int n   = bid >> 1;        // 0..351
    const int b   = n / 88, p = n - 88 * (n / 88);
    const int tid = threadIdx.x;     // 0..127
    const int u   = tid & 63;        // unit
    const int wv  = tid >> 6;        // 0: (i,g)  1: (f,o)
    const float* whh = dir ? whh_b : whh_f;
    const int j0 = dir ? 256 : 0;
    const int ho = dir ? 64 : 0;
    const int rowA = wv * 64 + u;          // i_u or f_u
    const int rowB = 128 + wv * 64 + u;    // g_u or o_u
    float wA[64], wB[64];
    #pragma unroll
    for (int k = 0; k < 64; k += 4) {
        const float4 wa = *(const float4*)(whh + (size_t)rowA * 64 + k);
        wA[k] = wa.x; wA[k+1] = wa.y; wA[k+2] = wa.z; wA[k+3] = wa.w;
        const float4 wb2 = *(const float4*)(whh + (size_t)rowB * 64 + k);
        wB[k] = wb2.x; wB[k+1] = wb2.y; wB[k+2] = wb2.z; wB[k+3] = wb2.w;
    }
    __shared__ float h_sh[64];
    __shared__ float ig_sh[64];
    if (tid < 64) h_sh[tid] = 0.0f;
    float c = 0.0f;
    __syncthreads();
    const size_t rowbase = (size_t)(b * 256) * 88 + p;
    const size_t r0 = rowbase + (size_t)(dir ? 255 : 0) * 88;
    float prefA = XI[r0 * 512 + j0 + rowA];
    float prefB = XI[r0 * 512 + j0 + rowB];
    for (int step = 0; step < 256; ++step) {
        const int t = dir ? (255 - step) : step;
        const size_t r = rowbase + (size_t)t * 88;
        float gA0 = prefA, gA1 = 0.0f, gB0 = prefB, gB1 = 0.0f;
        if (step + 1 < 256) {   // prefetch next step's xi (hides HBM latency)
            const int tn = dir ? (254 - step) : (step + 1);
            const size_t rn = rowbase + (size_t)tn * 88;
            prefA = XI[rn * 512 + j0 + rowA];
            prefB = XI[rn * 512 + j0 + rowB];
        }
        #pragma unroll
        for (int k = 0; k < 64; k += 8) {
            const float4 h0 = *(const float4*)&h_sh[k];
            const float4 h1 = *(const float4*)&h_sh[k + 4];
            gA0 += h0.x * wA[k]   + h0.y * wA[k+1] + h0.z * wA[k+2] + h0.w * wA[k+3];
            gA1 += h1.x * wA[k+4] + h1.y * wA[k+5] + h1.z * wA[k+6] + h1.w * wA[k+7];
            gB0 += h0.x * wB[k]   + h0.y * wB[k+1] + h0.z * wB[k+2] + h0.w * wB[k+3];
            gB1 += h1.x * wB[k+4] + h1.y * wB[k+5] + h1.z * wB[k+6] + h1.w * wB[k+7];
        }
        const float gAs = gA0 + gA1;          // i (wv0) or f (wv1)
        const float gBs = gB0 + gB1;          // g (wv0) or o (wv1)
        const float aA = 1.0f / (1.0f + __expf(-gAs));   // sigmoid for i / f
        float aB;
        if (wv == 0) {                        // g-gate: tanh (wave-uniform)
            const float e = __expf(2.0f * gBs);
            aB = 1.0f - 2.0f / (e + 1.0f);
        } else {                              // o-gate: sigmoid
            aB = 1.0f / (1.0f + __expf(-gBs));
        }
        if (wv == 0) ig_sh[u] = aA * aB;      // i*g
        __syncthreads();
        if (wv == 1) {
            c = aA * c + ig_sh[u];            // f*c + i*g
            const float e = __expf(2.0f * c);
            const float th = 1.0f - 2.0f / (e + 1.0f);
            const float h = aB * th;          // o * tanh(c)
            h_sh[u] = h;
            const size_t o = r * 128 + ho + u;
            const unsigned short hh = f2bf(h);
            Hh[o] = hh; Hl[o] = f2bf(h - bf2f(hh));
        }
        __syncthreads();
    }
}

// ---------------------------------------------------------------------------
// NA1D over t, kernel=7, heads=1. One wave per query row.
// QKV: [MROWS][384] f32 (q|k|v). OUT: hi/lo bf16 [MROWS][128].
// ---------------------------------------------------------------------------
__launch_bounds__(256)
__global__ void na_t_kernel(const float* __restrict__ QKV,
                            const float* __restrict__ rpb,
                            unsigned short* __restrict__ OUTh,
                            unsigned short* __restrict__ OUTl)
{
    const int wave = threadIdx.x >> 6;
    const int lane = threadIdx.x & 63;
    const int q = blockIdx.x * 4 + wave;          // row r = (b*256+i)*88+p
    const int b = q / TP; int rem = q - b * TP;
    const int i = rem / 88; const int p = rem - 88 * (rem / 88);
    int start = i - 3; if (start < 0) start = 0; if (start > 249) start = 249;
    const float scale = 0.08838834764831845f;     // 128^-0.5
    const float* qrow = QKV + (size_t)q * 384;
    const float q0 = qrow[lane] * scale;
    const float q1 = qrow[lane + 64] * scale;
    const size_t rbase = (size_t)(b * 256) * 88 + p;
    float s[7];
    #pragma unroll
    for (int jj = 0; jj < 7; ++jj) {
        const int t = start + jj;
        const float* krow = QKV + (rbase + (size_t)t * 88) * 384 + 128;
        float part = q0 * krow[lane] + q1 * krow[lane + 64];
        part += __shfl_xor(part, 1);
        part += __shfl_xor(part, 2);
        part += __shfl_xor(part, 4);
        part += __shfl_xor(part, 8);
        part += __shfl_xor(part, 16);
        part += __shfl_xor(part, 32);
        int rel = t - i + 6; if (rel < 0) rel = 0; if (rel > 12) rel = 12;
        s[jj] = part + rpb[rel];
    }
    float m = s[0];
    #pragma unroll
    for (int jj = 1; jj < 7; ++jj) m = fmaxf(m, s[jj]);
    float sum = 0.0f;
    #pragma unroll
    for (int jj = 0; jj < 7; ++jj) { s[jj] = __expf(s[jj] - m); sum += s[jj]; }
    const float inv = 1.0f / sum;
    float o0 = 0.0f, o1 = 0.0f;
    #pragma unroll
    for (int jj = 0; jj < 7; ++jj) {
        const float* vrow = QKV + (rbase + (size_t)(start + jj) * 88) * 384 + 256;
        const float pj = s[jj] * inv;
        o0 += pj * vrow[lane];
        o1 += pj * vrow[lane + 64];
    }
    const size_t oi = (size_t)q * 128 + lane;
    const unsigned short h0 = f2bf(o0);
    OUTh[oi] = h0; OUTl[oi] = f2bf(o0 - bf2f(h0));
    const unsigned short h1 = f2bf(o1);
    OUTh[oi + 64] = h1; OUTl[oi + 64] = f2bf(o1 - bf2f(h1));
}

// ---------------------------------------------------------------------------
// NA1D over p, kernel=87, L=88, heads=1. One block per (b,t).
// Excluded key: j=87 when i<=43, j=0 when i>=44. OUT: hi/lo bf16.
// ---------------------------------------------------------------------------
#define LPAD 133
#define SPAD 89
__launch_bounds__(256)
__global__ void na_f_kernel(const float* __restrict__ QKV,
                            const float* __restrict__ rpb,
                            unsigned short* __restrict__ OUTh,
                            unsigned short* __restrict__ OUTl)
{
    __shared__ float Qs[96][LPAD];
    __shared__ float Ks[96][LPAD];   // reused for V in PV phase
    __shared__ float Ss[96][SPAD];
    const int blk = blockIdx.x;                      // b*256 + t
    const int tid = threadIdx.x;
    const size_t base = (size_t)blk * 88 * 384;
    const float scale = 0.08838834764831845f;
    for (int f = tid; f < 2816; f += 256) {
        const int row = f >> 5, c4 = (f & 31) * 4;
        const float4 qv = *(const float4*)(QKV + base + (size_t)row * 384 + c4);
        Qs[row][c4+0] = qv.x * scale; Qs[row][c4+1] = qv.y * scale;
        Qs[row][c4+2] = qv.z * scale; Qs[row][c4+3] = qv.w * scale;
        const float4 kv = *(const float4*)(QKV + base + (size_t)row * 384 + 128 + c4);
        Ks[row][c4+0] = kv.x; Ks[row][c4+1] = kv.y;
        Ks[row][c4+2] = kv.z; Ks[row][c4+3] = kv.w;
    }
    __syncthreads();
    const int tx = tid & 15, ty = tid >> 4;
    { // S = Q K^T
        float acc[6][6] = {};
        for (int kk = 0; kk < 128; ++kk) {
            float a[6], bb[6];
            #pragma unroll
            for (int i = 0; i < 6; ++i) a[i] = Qs[ty*6 + i][kk];
            #pragma unroll
            for (int j = 0; j < 6; ++j) bb[j] = Ks[tx*6 + j][kk];
            #pragma unroll
            for (int i = 0; i < 6; ++i)
                #pragma unroll
                for (int j = 0; j < 6; ++j)
                    acc[i][j] += a[i] * bb[j];
        }
        #pragma unroll
        for (int i = 0; i < 6; ++i) {
            const int qq = ty*6 + i;
            if (qq < 88) {
                #pragma unroll
                for (int j = 0; j < 6; ++j) {
                    const int k = tx*6 + j;
                    if (k < 88) Ss[qq][k] = acc[i][j];
                }
            }
        }
    }
    __syncthreads();
    // stage V into Ks region (K no longer needed)
    for (int f = tid; f < 2816; f += 256) {
        const int row = f >> 5, c4 = (f & 31) * 4;
        const float4 vv = *(const float4*)(QKV + base + (size_t)row * 384 + 256 + c4);
        Ks[row][c4+0] = vv.x; Ks[row][c4+1] = vv.y;
        Ks[row][c4+2] = vv.z; Ks[row][c4+3] = vv.w;
    }
    if (tid < 88) {
        const int i = tid;
        const int jex = (i <= 43) ? 87 : 0;
        float m = -1e30f;
        for (int k = 0; k < 88; ++k) {
            if (k == jex) continue;
            int rel = k - i + 86; if (rel < 0) rel = 0; if (rel > 172) rel = 172;
            const float v = Ss[i][k] + rpb[rel];
            Ss[i][k] = v;
            m = fmaxf(m, v);
        }
        float sum = 0.0f;
        for (int k = 0; k < 88; ++k) {
            if (k == jex) continue;
            const float e = __expf(Ss[i][k] - m);
            Ss[i][k] = e;
            sum += e;
        }
        const float inv = 1.0f / sum;
        for (int k = 0; k < 88; ++k) Ss[i][k] = (k == jex) ? 0.0f : Ss[i][k] * inv;
    }
    __syncthreads();
    { // O = P V
        float o[6][8] = {};
        for (int k = 0; k < 88; ++k) {
            float pv[6], vv[8];
            #pragma unroll
            for (int i = 0; i < 6; ++i) pv[i] = Ss[ty*6 + i][k];
            #pragma unroll
            for (int j = 0; j < 8; ++j) vv[j] = Ks[k][tx + 16*j];
            #pragma unroll
            for (int i = 0; i < 6; ++i)
                #pragma unroll
                for (int j = 0; j < 8; ++j)
                    o[i][j] += pv[i] * vv[j];
        }
        #pragma unroll
        for (int i = 0; i < 6; ++i) {
            const int qq = ty*6 + i;
            if (qq < 88) {
                const size_t ro = ((size_t)blk * 88 + qq) * 128;
                #pragma unroll
                for (int j = 0; j < 8; ++j) {
                    const float v = o[i][j];
                    const unsigned short hh = f2bf(v);
                    OUTh[ro + tx + 16*j] = hh;
                    OUTl[ro + tx + 16*j] = f2bf(v - bf2f(hh));
                }
            }
        }
    }
}

// ---------------------------------------------------------------------------
extern "C" void kernel_launch(void* const* d_in, const int* in_sizes, int n_in,
                              void* d_out, int out_size, void* d_ws, size_t ws_size,
                              hipStream_t stream)
{
    const float* x         = (const float*)d_in[0];
    const float* w_ih_l0   = (const float*)d_in[1];
    const float* w_hh_l0   = (const float*)d_in[2];
    const float* b_ih_l0   = (const float*)d_in[3];
    const float* b_hh_l0   = (const float*)d_in[4];
    const float* w_ih_l0r  = (const float*)d_in[5];
    const float* w_hh_l0r  = (const float*)d_in[6];
    const float* b_ih_l0r  = (const float*)d_in[7];
    const float* b_hh_l0r  = (const float*)d_in[8];
    const float* w_ih_l1   = (const float*)d_in[9];
    const float* w_hh_l1   = (const float*)d_in[10];
    const float* b_ih_l1   = (const float*)d_in[11];
    const float* b_hh_l1   = (const float*)d_in[12];
    const float* w_ih_l1r  = (const float*)d_in[13];
    const float* w_hh_l1r  = (const float*)d_in[14];
    const float* b_ih_l1r  = (const float*)d_in[15];
    const float* b_hh_l1r  = (const float*)d_in[16];
    const float* qkv_w_t   = (const float*)d_in[17];
    const float* qkv_b_t   = (const float*)d_in[18];
    const float* rpb_t     = (const float*)d_in[19];
    const float* proj_w_t  = (const float*)d_in[20];
    const float* proj_b_t  = (const float*)d_in[21];
    const float* qkv_w_f   = (const float*)d_in[22];
    const float* qkv_b_f   = (const float*)d_in[23];
    const float* rpb_f     = (const float*)d_in[24];
    const float* proj_w_f  = (const float*)d_in[25];
    const float* proj_b_f  = (const float*)d_in[26];

    // Workspace (floats from base), ~278 MB:
    //  [0 .. 46,137,344)           XI f32 [MROWS][512]; later QKV f32
    //                              [MROWS][384] at base + ATT hi/lo pair in
    //                              the tail (exactly fits).
    //  [46,137,344 .. 57,671,680)  H hi/lo pair   (overlaid by Xhi initially)
    //  [57,671,680 .. 69,206,016)  G hi/lo pair   (overlaid by Xlo initially)
    //  [69,206,016 .. 69,533,696)  WH | WL weight bf16 pairs
    float* ws = (float*)d_ws;
    float*          XI   = ws;
    float*          QKV  = ws;
    unsigned short* ATTh = (unsigned short*)(ws + (size_t)MROWS * 384);
    unsigned short* ATTl = ATTh + (size_t)MROWS * 128;
    unsigned short* Hh   = (unsigned short*)(ws + 46137344);
    unsigned short* Hl   = Hh + (size_t)MROWS * 128;
    unsigned short* Gh   = (unsigned short*)(ws + 57671680);
    unsigned short* Gl   = Gh + (size_t)MROWS * 128;
    unsigned short* Xh   = (unsigned short*)(ws + 46137344);  // overlay H+G
    unsigned short* Xl   = Xh + (size_t)MROWS * 256;
    unsigned short* WH   = (unsigned short*)(ws + 69206016);
    unsigned short* WL   = WH + 327680;

    const int BIG = 1 << 30;
    const dim3 blk(256);

    convert_w<<<dim3(320), blk, 0, stream>>>(w_ih_l0, w_ih_l0r, w_ih_l1, w_ih_l1r,
        qkv_w_t, proj_w_t, qkv_w_f, proj_w_f, WH, WL);
    transpose_x<<<dim3(352, 4, 4), blk, 0, stream>>>(x, Xh, Xl);
    // 1) layer-0 input projection
    gemm_bf16<0><<<dim3(2816), blk, 0, stream>>>(Xh, Xl,
        WH, WL, WH + 65536, WL + 65536,
        b_ih_l0, b_hh_l0, b_ih_l0r, b_hh_l0r,
        XI, nullptr, nullptr, 512, 256, 256, 4);
    // 2) layer-0 recurrence
    lstm_kernel<<<dim3(704), dim3(128), 0, stream>>>(XI, w_hh_l0, w_hh_l0r, Hh, Hl);
    // 3) layer-1 input projection
    gemm_bf16<0><<<dim3(2816), blk, 0, stream>>>(Hh, Hl,
        WH + 131072, WL + 131072, WH + 163840, WL + 163840,
        b_ih_l1, b_hh_l1, b_ih_l1r, b_hh_l1r,
        XI, nullptr, nullptr, 512, 128, 256, 4);
    // 4) layer-1 recurrence
    lstm_kernel<<<dim3(704), dim3(128), 0, stream>>>(XI, w_hh_l1, w_hh_l1r, Hh, Hl);
    // 5) QKV for NA over t
    gemm_bf16<0><<<dim3(2112), blk, 0, stream>>>(Hh, Hl,
        WH + 196608, WL + 196608, WH + 196608, WL + 196608,
        qkv_b_t, nullptr, qkv_b_t, nullptr,
        QKV, nullptr, nullptr, 384, 128, BIG, 3);
    // 6) NA over t (kernel=7)
    na_t_kernel<<<dim3(22528), blk, 0, stream>>>(QKV, rpb_t, ATTh, ATTl);
    // 7) proj_t -> G (bf16 pair out)
    gemm_bf16<1><<<dim3(704), blk, 0, stream>>>(ATTh, ATTl,
        WH + 245760, WL + 245760, WH + 245760, WL + 245760,
        proj_b_t, nullptr, proj_b_t, nullptr,
        nullptr, Gh, Gl, 128, 128, BIG, 1);
    // 8) QKV for NA over p
    gemm_bf16<0><<<dim3(2112), blk, 0, stream>>>(Gh, Gl,
        WH + 262144, WL + 262144, WH + 262144, WL + 262144,
        qkv_b_f, nullptr, qkv_b_f, nullptr,
        QKV, nullptr, nullptr, 384, 128, BIG, 3);
    // 9) NA over p (kernel=87)
    na_f_kernel<<<dim3(1024), blk, 0, stream>>>(QKV, rpb_f, ATTh, ATTl);
    // 10) proj_f -> final output
    gemm_bf16<0><<<dim3(704), blk, 0, stream>>>(ATTh, ATTl,
        WH + 311296, WL + 311296, WH + 311296, WL + 311296,
        proj_b_f, nullptr, proj_b_f, nullptr,
        (float*)d_out, nullptr, nullptr, 128, 128, BIG, 1);
}

// Round 9
// 1056.217 us; speedup vs baseline: 1.2223x; 1.1092x over previous
//
#include <hip/hip_runtime.h>
#include <cstdint>

#define TP 22528            // 256*88  (t,p) plane size
#define MROWS 90112         // 4*256*88

typedef __bf16 bf16x8 __attribute__((ext_vector_type(8)));
typedef float  f32x4  __attribute__((ext_vector_type(4)));
typedef unsigned short ushort8 __attribute__((ext_vector_type(8)));

__device__ __forceinline__ unsigned short f2bf(float x) {
    unsigned u = __builtin_bit_cast(unsigned, x);
    return (unsigned short)((u + 0x7fffu + ((u >> 16) & 1u)) >> 16);
}
__device__ __forceinline__ float bf2f(unsigned short h) {
    return __builtin_bit_cast(float, (unsigned)h << 16);
}
__device__ __forceinline__ void gl16(const void* g, void* l) {
    __builtin_amdgcn_global_load_lds(
        (const __attribute__((address_space(1))) void*)g,
        (__attribute__((address_space(3))) void*)l, 16, 0, 0);
}

// ---------------------------------------------------------------------------
// convert all 8 weight matrices f32 -> (hi,lo) bf16, concatenated in WH/WL.
// ---------------------------------------------------------------------------
__global__ void convert_w(const float* __restrict__ s0, const float* __restrict__ s1,
                          const float* __restrict__ s2, const float* __restrict__ s3,
                          const float* __restrict__ s4, const float* __restrict__ s5,
                          const float* __restrict__ s6, const float* __restrict__ s7,
                          unsigned short* __restrict__ WH, unsigned short* __restrict__ WL)
{
    const int stride = gridDim.x * blockDim.x;
    for (int i = blockIdx.x * blockDim.x + threadIdx.x; i < 327680; i += stride) {
        const float* s; int base;
        if      (i <  65536) { s = s0; base = 0; }
        else if (i < 131072) { s = s1; base = 65536; }
        else if (i < 163840) { s = s2; base = 131072; }
        else if (i < 196608) { s = s3; base = 163840; }
        else if (i < 245760) { s = s4; base = 196608; }
        else if (i < 262144) { s = s5; base = 245760; }
        else if (i < 311296) { s = s6; base = 262144; }
        else                 { s = s7; base = 311296; }
        const float v = s[i - base];
        const unsigned short h = f2bf(v);
        WH[i] = h; WL[i] = f2bf(v - bf2f(h));
    }
}

// ---------------------------------------------------------------------------
// x (4, 256, 256, 88) f32  ->  Xhi/Xlo [m=(b,t,p)][k=256] bf16 (tiled transpose)
// ---------------------------------------------------------------------------
__launch_bounds__(256)
__global__ void transpose_x(const float* __restrict__ x,
                            unsigned short* __restrict__ Xh,
                            unsigned short* __restrict__ Xl)
{
    __shared__ float tile[64][65];
    const int tid = threadIdx.x;
    const int tp0 = blockIdx.x * 64, k0 = blockIdx.y * 64, b = blockIdx.z;
    #pragma unroll
    for (int i = 0; i < 16; ++i) {
        const int idx = i * 256 + tid;
        const int kl = idx >> 6, tpl = idx & 63;
        tile[kl][tpl] = x[(size_t)(b * 256 + k0 + kl) * TP + tp0 + tpl];
    }
    __syncthreads();
    #pragma unroll
    for (int i = 0; i < 2; ++i) {
        const int u = i * 2048 + tid * 8;
        const int ml = u >> 6, kl0 = u & 63;
        ushort8 hi, lo;
        #pragma unroll
        for (int j = 0; j < 8; ++j) {
            const float v = tile[kl0 + j][ml];
            const unsigned short h = f2bf(v);
            hi[j] = h; lo[j] = f2bf(v - bf2f(h));
        }
        const size_t row = (size_t)b * TP + tp0 + ml;
        *(ushort8*)&Xh[row * 256 + k0 + kl0] = hi;
        *(ushort8*)&Xl[row * 256 + k0 + kl0] = lo;
    }
}

// ---------------------------------------------------------------------------
// MFMA split-bf16 GEMM, pre-converted operands. (unchanged, passing)
// ---------------------------------------------------------------------------
template<int OUTBF>
__launch_bounds__(256, 2)
__global__ void gemm_bf16(const unsigned short* __restrict__ Ahi,
                          const unsigned short* __restrict__ Alo,
                          const unsigned short* __restrict__ Whi0,
                          const unsigned short* __restrict__ Wlo0,
                          const unsigned short* __restrict__ Whi1,
                          const unsigned short* __restrict__ Wlo1,
                          const float* __restrict__ b0a, const float* __restrict__ b0b,
                          const float* __restrict__ b1a, const float* __restrict__ b1b,
                          float* __restrict__ C,
                          unsigned short* __restrict__ Chi, unsigned short* __restrict__ Clo,
                          int ldc, int K, int splitN, int NB)
{
    __shared__ unsigned short lds[32768];   // 2 bufs x (AH|AL|BH|BL) x 8KB
    const int tid  = threadIdx.x;
    const int bid  = blockIdx.x;
    const int q8   = (int)gridDim.x >> 3;
    const int wq   = (bid & 7) * q8 + (bid >> 3);   // bijective XCD swizzle
    const int nb   = wq % NB;
    const int mb   = wq / NB;
    const int n0   = nb * 128;
    const int m0   = mb * 128;
    const unsigned short* Wh; const unsigned short* Wl;
    const float* ba; const float* bb; int nr0;
    if (n0 < splitN) { Wh = Whi0; Wl = Wlo0; ba = b0a; bb = b0b; nr0 = n0; }
    else             { Wh = Whi1; Wl = Wlo1; ba = b1a; bb = b1b; nr0 = n0 - splitN; }
    const int lane = tid & 63;
    const int wv   = tid >> 6;
    const int wm   = wv >> 1, wn = wv & 1;
    const int lr   = lane & 15, lg = lane >> 4;
    const int voff = (lane >> 2) * K + (((lane & 3) ^ ((lane >> 2) & 3)) * 8);
    const int wb   = wv * 1024;

    const unsigned short* gAh = Ahi + (size_t)(m0 + wv * 32) * K + voff;
    const unsigned short* gAl = Alo + (size_t)(m0 + wv * 32) * K + voff;
    const unsigned short* gBh = Wh + (size_t)(nr0 + wv * 32) * K + voff;
    const unsigned short* gBl = Wl + (size_t)(nr0 + wv * 32) * K + voff;

    const int NT = K >> 5;
    f32x4 acc[4][4] = {};

    auto stage = [&](int bufi, int ks) {
        unsigned short* base = lds + bufi * 16384;
        gl16(gAh + ks,          base +         wb);
        gl16(gAh + ks + 16 * K, base +         wb + 512);
        gl16(gAl + ks,          base + 4096  + wb);
        gl16(gAl + ks + 16 * K, base + 4096  + wb + 512);
        gl16(gBh + ks,          base + 8192  + wb);
        gl16(gBh + ks + 16 * K, base + 8192  + wb + 512);
        gl16(gBl + ks,          base + 12288 + wb);
        gl16(gBl + ks + 16 * K, base + 12288 + wb + 512);
    };

    stage(0, 0);
    for (int t = 0; t < NT; ++t) {
        const int cur = (t & 1) * 16384;
        if (t + 1 < NT) {
            stage((t & 1) ^ 1, (t + 1) * 32);
            asm volatile("s_waitcnt vmcnt(8)" ::: "memory");
        } else {
            asm volatile("s_waitcnt vmcnt(0)" ::: "memory");
        }
        __builtin_amdgcn_s_barrier();
        __builtin_amdgcn_sched_barrier(0);
        bf16x8 ah[4], al[4], bh[4], bl[4];
        #pragma unroll
        for (int mf = 0; mf < 4; ++mf) {
            const int r = wm * 64 + mf * 16 + lr;
            const int o = r * 32 + ((lg ^ (r & 3)) * 8);
            ah[mf] = *(const bf16x8*)&lds[cur + o];
            al[mf] = *(const bf16x8*)&lds[cur + 4096 + o];
        }
        #pragma unroll
        for (int nf = 0; nf < 4; ++nf) {
            const int r = wn * 64 + nf * 16 + lr;
            const int o = r * 32 + ((lg ^ (r & 3)) * 8);
            bh[nf] = *(const bf16x8*)&lds[cur + 8192 + o];
            bl[nf] = *(const bf16x8*)&lds[cur + 12288 + o];
        }
        #pragma unroll
        for (int mf = 0; mf < 4; ++mf)
            #pragma unroll
            for (int nf = 0; nf < 4; ++nf) {
                acc[mf][nf] = __builtin_amdgcn_mfma_f32_16x16x32_bf16(ah[mf], bh[nf], acc[mf][nf], 0, 0, 0);
                acc[mf][nf] = __builtin_amdgcn_mfma_f32_16x16x32_bf16(ah[mf], bl[nf], acc[mf][nf], 0, 0, 0);
                acc[mf][nf] = __builtin_amdgcn_mfma_f32_16x16x32_bf16(al[mf], bh[nf], acc[mf][nf], 0, 0, 0);
            }
        __builtin_amdgcn_s_barrier();
        __builtin_amdgcn_sched_barrier(0);
    }
    #pragma unroll
    for (int nf = 0; nf < 4; ++nf) {
        const int ncol = wn * 64 + nf * 16 + lr;
        const float bias = ba[nr0 + ncol] + (bb ? bb[nr0 + ncol] : 0.0f);
        #pragma unroll
        for (int mf = 0; mf < 4; ++mf) {
            const int row = m0 + wm * 64 + mf * 16 + lg * 4;
            #pragma unroll
            for (int i = 0; i < 4; ++i) {
                const float v = acc[mf][nf][i] + bias;
                if (OUTBF) {
                    const size_t o = (size_t)(row + i) * ldc + n0 + ncol;
                    const unsigned short h = f2bf(v);
                    Chi[o] = h; Clo[o] = f2bf(v - bf2f(h));
                } else {
                    C[(size_t)(row + i) * ldc + n0 + ncol] = v;
                }
            }
        }
    }
}

// ---------------------------------------------------------------------------
// LSTM recurrence — EXACT round-4 version (best measured: 228 us/launch,
// LDS-broadcast-bound floor for this dataflow). One 256-thread block per
// (row, dir); thread j owns gate j; threads 0..63 own (c,h). Gate order
// i|f|g|o. 16 uniform ds_read_b128/thread/step; XI prefetch; 4-way split acc.
// ---------------------------------------------------------------------------
__launch_bounds__(256)
__global__ void lstm_kernel(const float* __restrict__ XI,
                            const float* __restrict__ whh_f,
                            const float* __restrict__ whh_b,
                            unsigned short* __restrict__ Hh,
                            unsigned short* __restrict__ Hl)
{
    const int bid = blockIdx.x;      // 0..703
    const int dir = bid & 1;
    const int n   = bid >> 1;        // 0..351
    const int b   = n / 88, p = n - 88 * (n / 88);
    const int j   = threadIdx.x;
    const float* whh = dir ? whh_b : whh_f;
    const int j0 = dir ? 256 : 0;
    const int ho = dir ? 64 : 0;
    float w[64];
    #pragma unroll
    for (int k = 0; k < 64; k += 4) {
        const float4 wv = *(const float4*)(whh + (size_t)j * 64 + k);
        w[k] = wv.x; w[k+1] = wv.y; w[k+2] = wv.z; w[k+3] = wv.w;
    }
    __shared__ float h_sh[64];
    __shared__ float acts[256];
    if (j < 64) h_sh[j] = 0.0f;
    float c = 0.0f;
    __syncthreads();
    const size_t rowbase = (size_t)(b * 256) * 88 + p;
    float pref = XI[(rowbase + (size_t)(dir ? 255 : 0) * 88) * 512 + j0 + j];
    for (int step = 0; step < 256; ++step) {
        const int t = dir ? (255 - step) : step;
        const size_t r = rowbase + (size_t)t * 88;
        float gs0 = pref, gs1 = 0.0f, gs2 = 0.0f, gs3 = 0.0f;
        if (step + 1 < 256) {   // prefetch next step's xi (hides HBM latency)
            const int tn = dir ? (254 - step) : (step + 1);
            pref = XI[(rowbase + (size_t)tn * 88) * 512 + j0 + j];
        }
        #pragma unroll
        for (int k = 0; k < 64; k += 16) {
            const float4 h0 = *(const float4*)&h_sh[k];
            const float4 h1 = *(const float4*)&h_sh[k + 4];
            const float4 h2 = *(const float4*)&h_sh[k + 8];
            const float4 h3 = *(const float4*)&h_sh[k + 12];
            gs0 += h0.x * w[k]    + h0.y * w[k+1]  + h0.z * w[k+2]  + h0.w * w[k+3];
            gs1 += h1.x * w[k+4]  + h1.y * w[k+5]  + h1.z * w[k+6]  + h1.w * w[k+7];
            gs2 += h2.x * w[k+8]  + h2.y * w[k+9]  + h2.z * w[k+10] + h2.w * w[k+11];
            gs3 += h3.x * w[k+12] + h3.y * w[k+13] + h3.z * w[k+14] + h3.w * w[k+15];
        }
        const float g = (gs0 + gs1) + (gs2 + gs3);
        float a;
        if (j >= 128 && j < 192) {            // g-gate: tanh (wave-uniform)
            const float e = __expf(2.0f * g);
            a = 1.0f - 2.0f / (e + 1.0f);
        } else {                              // i,f,o: sigmoid
            a = 1.0f / (1.0f + __expf(-g));
        }
        acts[j] = a;
        __syncthreads();
        if (j < 64) {
            const float ai = acts[j], af = acts[64 + j], ag = acts[128 + j], ao = acts[192 + j];
            c = af * c + ai * ag;
            const float e = __expf(2.0f * c);
            const float th = 1.0f - 2.0f / (e + 1.0f);
            const float h = ao * th;
            h_sh[j] = h;
            const size_t o = r * 128 + ho + j;
            const unsigned short hh = f2bf(h);
            Hh[o] = hh; Hl[o] = f2bf(h - bf2f(hh));
        }
        __syncthreads();
    }
}

// ---------------------------------------------------------------------------
// NA1D over t, kernel=7, heads=1. One wave per query row. (unchanged)
// ---------------------------------------------------------------------------
__launch_bounds__(256)
__global__ void na_t_kernel(const float* __restrict__ QKV,
                            const float* __restrict__ rpb,
                            unsigned short* __restrict__ OUTh,
                            unsigned short* __restrict__ OUTl)
{
    const int wave = threadIdx.x >> 6;
    const int lane = threadIdx.x & 63;
    const int q = blockIdx.x * 4 + wave;          // row r = (b*256+i)*88+p
    const int b = q / TP; int rem = q - b * TP;
    const int i = rem / 88; const int p = rem - 88 * (rem / 88);
    int start = i - 3; if (start < 0) start = 0; if (start > 249) start = 249;
    const float scale = 0.08838834764831845f;     // 128^-0.5
    const float* qrow = QKV + (size_t)q * 384;
    const float q0 = qrow[lane] * scale;
    const float q1 = qrow[lane + 64] * scale;
    const size_t rbase = (size_t)(b * 256) * 88 + p;
    float s[7];
    #pragma unroll
    for (int jj = 0; jj < 7; ++jj) {
        const int t = start + jj;
        const float* krow = QKV + (rbase + (size_t)t * 88) * 384 + 128;
        float part = q0 * krow[lane] + q1 * krow[lane + 64];
        part += __shfl_xor(part, 1);
        part += __shfl_xor(part, 2);
        part += __shfl_xor(part, 4);
        part += __shfl_xor(part, 8);
        part += __shfl_xor(part, 16);
        part += __shfl_xor(part, 32);
        int rel = t - i + 6; if (rel < 0) rel = 0; if (rel > 12) rel = 12;
        s[jj] = part + rpb[rel];
    }
    float m = s[0];
    #pragma unroll
    for (int jj = 1; jj < 7; ++jj) m = fmaxf(m, s[jj]);
    float sum = 0.0f;
    #pragma unroll
    for (int jj = 0; jj < 7; ++jj) { s[jj] = __expf(s[jj] - m); sum += s[jj]; }
    const float inv = 1.0f / sum;
    float o0 = 0.0f, o1 = 0.0f;
    #pragma unroll
    for (int jj = 0; jj < 7; ++jj) {
        const float* vrow = QKV + (rbase + (size_t)(start + jj) * 88) * 384 + 256;
        const float pj = s[jj] * inv;
        o0 += pj * vrow[lane];
        o1 += pj * vrow[lane + 64];
    }
    const size_t oi = (size_t)q * 128 + lane;
    const unsigned short h0 = f2bf(o0);
    OUTh[oi] = h0; OUTl[oi] = f2bf(o0 - bf2f(h0));
    const unsigned short h1 = f2bf(o1);
    OUTh[oi + 64] = h1; OUTl[oi + 64] = f2bf(o1 - bf2f(h1));
}

// ---------------------------------------------------------------------------
// NA1D over p, kernel=87, L=88, heads=1. One block per (b,t).
// (1) rpb + exclusion mask fused into S epilogue (excluded key -> -1e30 ->
//     exp=0 -> normalized 0; rel clamped to [0,172] for speculative-load
//     safety — only masked pairs would go OOB, verified qq=87/k=0, qq=0/k=87).
// (2) softmax 2 threads/row + shfl_xor(1) combine (serial 88 -> 44).
// ---------------------------------------------------------------------------
#define LPAD 133
#define SPAD 89
__launch_bounds__(256)
__global__ void na_f_kernel(const float* __restrict__ QKV,
                            const float* __restrict__ rpb,
                            unsigned short* __restrict__ OUTh,
                            unsigned short* __restrict__ OUTl)
{
    __shared__ float Qs[96][LPAD];
    __shared__ float Ks[96][LPAD];   // reused for V in PV phase
    __shared__ float Ss[96][SPAD];
    const int blk = blockIdx.x;                      // b*256 + t
    const int tid = threadIdx.x;
    const size_t base = (size_t)blk * 88 * 384;
    const float scale = 0.08838834764831845f;
    for (int f = tid; f < 2816; f += 256) {
        const int row = f >> 5, c4 = (f & 31) * 4;
        const float4 qv = *(const float4*)(QKV + base + (size_t)row * 384 + c4);
        Qs[row][c4+0] = qv.x * scale; Qs[row][c4+1] = qv.y * scale;
        Qs[row][c4+2] = qv.z * scale; Qs[row][c4+3] = qv.w * scale;
        const float4 kv = *(const float4*)(QKV + base + (size_t)row * 384 + 128 + c4);
        Ks[row][c4+0] = kv.x; Ks[row][c4+1] = kv.y;
        Ks[row][c4+2] = kv.z; Ks[row][c4+3] = kv.w;
    }
    __syncthreads();
    const int tx = tid & 15, ty = tid >> 4;
    { // S = Q K^T  (+ rpb bias + exclusion mask fused)
        float acc[6][6] = {};
        for (int kk = 0; kk < 128; ++kk) {
            float a[6], bb[6];
            #pragma unroll
            for (int i = 0; i < 6; ++i) a[i] = Qs[ty*6 + i][kk];
            #pragma unroll
            for (int j = 0; j < 6; ++j) bb[j] = Ks[tx*6 + j][kk];
            #pragma unroll
            for (int i = 0; i < 6; ++i)
                #pragma unroll
                for (int j = 0; j < 6; ++j)
                    acc[i][j] += a[i] * bb[j];
        }
        #pragma unroll
        for (int i = 0; i < 6; ++i) {
            const int qq = ty*6 + i;
            if (qq < 88) {
                const int jex = (qq <= 43) ? 87 : 0;
                #pragma unroll
                for (int j = 0; j < 6; ++j) {
                    const int k = tx*6 + j;
                    if (k < 88) {
                        int rel = k - qq + 86;
                        rel = rel < 0 ? 0 : (rel > 172 ? 172 : rel);
                        Ss[qq][k] = (k == jex) ? -1e30f : acc[i][j] + rpb[rel];
                    }
                }
            }
        }
    }
    __syncthreads();
    // stage V into Ks region (K no longer needed)
    for (int f = tid; f < 2816; f += 256) {
        const int row = f >> 5, c4 = (f & 31) * 4;
        const float4 vv = *(const float4*)(QKV + base + (size_t)row * 384 + 256 + c4);
        Ks[row][c4+0] = vv.x; Ks[row][c4+1] = vv.y;
        Ks[row][c4+2] = vv.z; Ks[row][c4+3] = vv.w;
    }
    // softmax: 2 threads per row (halves k each), shfl_xor(1) combines
    if (tid < 176) {
        const int rrow = tid >> 1, hf = tid & 1;
        const int k0 = hf * 44;
        float m = -1e30f;
        for (int k = k0; k < k0 + 44; ++k) m = fmaxf(m, Ss[rrow][k]);
        m = fmaxf(m, __shfl_xor(m, 1));
        float sum = 0.0f;
        for (int k = k0; k < k0 + 44; ++k) {
            const float e = __expf(Ss[rrow][k] - m);
            Ss[rrow][k] = e;
            sum += e;
        }
        sum += __shfl_xor(sum, 1);
        const float inv = 1.0f / sum;
        for (int k = k0; k < k0 + 44; ++k) Ss[rrow][k] *= inv;
    }
    __syncthreads();
    { // O = P V
        float o[6][8] = {};
        for (int k = 0; k < 88; ++k) {
            float pv[6], vv[8];
            #pragma unroll
            for (int i = 0; i < 6; ++i) pv[i] = Ss[ty*6 + i][k];
            #pragma unroll
            for (int j = 0; j < 8; ++j) vv[j] = Ks[k][tx + 16*j];
            #pragma unroll
            for (int i = 0; i < 6; ++i)
                #pragma unroll
                for (int j = 0; j < 8; ++j)
                    o[i][j] += pv[i] * vv[j];
        }
        #pragma unroll
        for (int i = 0; i < 6; ++i) {
            const int qq = ty*6 + i;
            if (qq < 88) {
                const size_t ro = ((size_t)blk * 88 + qq) * 128;
                #pragma unroll
                for (int j = 0; j < 8; ++j) {
                    const float v = o[i][j];
                    const unsigned short hh = f2bf(v);
                    OUTh[ro + tx + 16*j] = hh;
                    OUTl[ro + tx + 16*j] = f2bf(v - bf2f(hh));
                }
            }
        }
    }
}

// ---------------------------------------------------------------------------
extern "C" void kernel_launch(void* const* d_in, const int* in_sizes, int n_in,
                              void* d_out, int out_size, void* d_ws, size_t ws_size,
                              hipStream_t stream)
{
    const float* x         = (const float*)d_in[0];
    const float* w_ih_l0   = (const float*)d_in[1];
    const float* w_hh_l0   = (const float*)d_in[2];
    const float* b_ih_l0   = (const float*)d_in[3];
    const float* b_hh_l0   = (const float*)d_in[4];
    const float* w_ih_l0r  = (const float*)d_in[5];
    const float* w_hh_l0r  = (const float*)d_in[6];
    const float* b_ih_l0r  = (const float*)d_in[7];
    const float* b_hh_l0r  = (const float*)d_in[8];
    const float* w_ih_l1   = (const float*)d_in[9];
    const float* w_hh_l1   = (const float*)d_in[10];
    const float* b_ih_l1   = (const float*)d_in[11];
    const float* b_hh_l1   = (const float*)d_in[12];
    const float* w_ih_l1r  = (const float*)d_in[13];
    const float* w_hh_l1r  = (const float*)d_in[14];
    const float* b_ih_l1r  = (const float*)d_in[15];
    const float* b_hh_l1r  = (const float*)d_in[16];
    const float* qkv_w_t   = (const float*)d_in[17];
    const float* qkv_b_t   = (const float*)d_in[18];
    const float* rpb_t     = (const float*)d_in[19];
    const float* proj_w_t  = (const float*)d_in[20];
    const float* proj_b_t  = (const float*)d_in[21];
    const float* qkv_w_f   = (const float*)d_in[22];
    const float* qkv_b_f   = (const float*)d_in[23];
    const float* rpb_f     = (const float*)d_in[24];
    const float* proj_w_f  = (const float*)d_in[25];
    const float* proj_b_f  = (const float*)d_in[26];

    float* ws = (float*)d_ws;
    float*          XI   = ws;
    float*          QKV  = ws;
    unsigned short* ATTh = (unsigned short*)(ws + (size_t)MROWS * 384);
    unsigned short* ATTl = ATTh + (size_t)MROWS * 128;
    unsigned short* Hh   = (unsigned short*)(ws + 46137344);
    unsigned short* Hl   = Hh + (size_t)MROWS * 128;
    unsigned short* Gh   = (unsigned short*)(ws + 57671680);
    unsigned short* Gl   = Gh + (size_t)MROWS * 128;
    unsigned short* Xh   = (unsigned short*)(ws + 46137344);  // overlay H+G
    unsigned short* Xl   = Xh + (size_t)MROWS * 256;
    unsigned short* WH   = (unsigned short*)(ws + 69206016);
    unsigned short* WL   = WH + 327680;

    const int BIG = 1 << 30;
    const dim3 blk(256);

    convert_w<<<dim3(320), blk, 0, stream>>>(w_ih_l0, w_ih_l0r, w_ih_l1, w_ih_l1r,
        qkv_w_t, proj_w_t, qkv_w_f, proj_w_f, WH, WL);
    transpose_x<<<dim3(352, 4, 4), blk, 0, stream>>>(x, Xh, Xl);
    // 1) layer-0 input projection
    gemm_bf16<0><<<dim3(2816), blk, 0, stream>>>(Xh, Xl,
        WH, WL, WH + 65536, WL + 65536,
        b_ih_l0, b_hh_l0, b_ih_l0r, b_hh_l0r,
        XI, nullptr, nullptr, 512, 256, 256, 4);
    // 2) layer-0 recurrence
    lstm_kernel<<<dim3(704), blk, 0, stream>>>(XI, w_hh_l0, w_hh_l0r, Hh, Hl);
    // 3) layer-1 input projection
    gemm_bf16<0><<<dim3(2816), blk, 0, stream>>>(Hh, Hl,
        WH + 131072, WL + 131072, WH + 163840, WL + 163840,
        b_ih_l1, b_hh_l1, b_ih_l1r, b_hh_l1r,
        XI, nullptr, nullptr, 512, 128, 256, 4);
    // 4) layer-1 recurrence
    lstm_kernel<<<dim3(704), blk, 0, stream>>>(XI, w_hh_l1, w_hh_l1r, Hh, Hl);
    // 5) QKV for NA over t
    gemm_bf16<0><<<dim3(2112), blk, 0, stream>>>(Hh, Hl,
        WH + 196608, WL + 196608, WH + 196608, WL + 196608,
        qkv_b_t, nullptr, qkv_b_t, nullptr,
        QKV, nullptr, nullptr, 384, 128, BIG, 3);
    // 6) NA over t (kernel=7)
    na_t_kernel<<<dim3(22528), blk, 0, stream>>>(QKV, rpb_t, ATTh, ATTl);
    // 7) proj_t -> G (bf16 pair out)
    gemm_bf16<1><<<dim3(704), blk, 0, stream>>>(ATTh, ATTl,
        WH + 245760, WL + 245760, WH + 245760, WL + 245760,
        proj_b_t, nullptr, proj_b_t, nullptr,
        nullptr, Gh, Gl, 128, 128, BIG, 1);
    // 8) QKV for NA over p
    gemm_bf16<0><<<dim3(2112), blk, 0, stream>>>(Gh, Gl,
        WH + 262144, WL + 262144, WH + 262144, WL + 262144,
        qkv_b_f, nullptr, qkv_b_f, nullptr,
        QKV, nullptr, nullptr, 384, 128, BIG, 3);
    // 9) NA over p (kernel=87)
    na_f_kernel<<<dim3(1024), blk, 0, stream>>>(QKV, rpb_f, ATTh, ATTl);
    // 10) proj_f -> final output
    gemm_bf16<0><<<dim3(704), blk, 0, stream>>>(ATTh, ATTl,
        WH + 311296, WL + 311296, WH + 311296, WL + 311296,
        proj_b_f, nullptr, proj_b_f, nullptr,
        (float*)d_out, nullptr, nullptr, 128, 128, BIG, 1);
}